// Round 15
// baseline (546.356 us; speedup 1.0000x reference)
//
#include <hip/hip_runtime.h>
#include <math.h>

typedef unsigned short u16;
typedef __attribute__((ext_vector_type(8))) short bf16x8;
typedef __attribute__((ext_vector_type(4))) float f32x4;

#define B_N 8
#define LSEQ 2048
#define D_INx 1024
#define D_MODELx 1024
#define D_STATEx 128
#define D_INNERx 2048
#define NHEADSx 32
#define HEADDIMx 64
#define CONV_DIMx 2304
#define D_IN_PROJx 4384
#define CHUNKx 64
#define NCHUNKx 32
#define NTOK (B_N*LSEQ)   // 16384

#define LDX 2336
#define XB_B 2048
#define XB_C 2176
#define XB_DT 2304

// ---------- bf16 helpers (storage only; math fp32) ----------
__device__ __forceinline__ float b2f(u16 u) {
    return __uint_as_float(((unsigned)u) << 16);
}
__device__ __forceinline__ u16 f2b(float f) {
    unsigned u = __float_as_uint(f);
    return (u16)((u + 0x7FFFu + ((u >> 16) & 1u)) >> 16);  // RNE
}
__device__ __forceinline__ void up8(uint4 v, float* f) {
    f[0] = b2f((u16)(v.x & 0xffff)); f[1] = b2f((u16)(v.x >> 16));
    f[2] = b2f((u16)(v.y & 0xffff)); f[3] = b2f((u16)(v.y >> 16));
    f[4] = b2f((u16)(v.z & 0xffff)); f[5] = b2f((u16)(v.z >> 16));
    f[6] = b2f((u16)(v.w & 0xffff)); f[7] = b2f((u16)(v.w >> 16));
}
__device__ __forceinline__ uint4 pk8(const float* f) {
    uint4 v;
    v.x = (unsigned)f2b(f[0]) | ((unsigned)f2b(f[1]) << 16);
    v.y = (unsigned)f2b(f[2]) | ((unsigned)f2b(f[3]) << 16);
    v.z = (unsigned)f2b(f[4]) | ((unsigned)f2b(f[5]) << 16);
    v.w = (unsigned)f2b(f[6]) | ((unsigned)f2b(f[7]) << 16);
    return v;
}

__device__ __forceinline__ float block_sum(float v) {
    __shared__ float sm[8];
    int lane = threadIdx.x & 63, wid = threadIdx.x >> 6;
    #pragma unroll
    for (int o = 32; o; o >>= 1) v += __shfl_xor(v, o);
    __syncthreads();
    if (lane == 0) sm[wid] = v;
    __syncthreads();
    float r = 0.f;
    int nw = blockDim.x >> 6;
    for (int w = 0; w < nw; ++w) r += sm[w];
    return r;
}

__device__ __forceinline__ float silu_f(float x) {
    return x / (1.f + expf(-x));
}

// ---------- fp32 -> bf16 conversion ----------
__global__ __launch_bounds__(256) void cvt_f2b_k(const float* __restrict__ in,
                                                 u16* __restrict__ out, int n4) {
    int i = blockIdx.x * 256 + threadIdx.x;
    if (i >= n4) return;
    float4 v = ((const float4*)in)[i];
    ushort4 o;
    o.x = f2b(v.x); o.y = f2b(v.y); o.z = f2b(v.z); o.w = f2b(v.w);
    ((ushort4*)out)[i] = o;
}

// ---------- bf16 MFMA GEMM v9: ring-4, DRIFT schedule (no mid-barrier) + LDS-transpose epilogue ----------
// C[M,N] = A[M,K] @ W[N,K]^T (+bias). M%256==0, K%128==0.
// Per phase q: {12 ds_reads(slot q&3); STAGE(q+3)->slot (q-1)&3; lgkmcnt(0)
// [own reads only — waves drift, so one wave's MFMA overlaps another's reads];
// 32 MFMA; counted vmcnt(8); barrier}. Hazard audit: stage(q+3) overwrites
// slot (q-1) whose readers all passed their own lgkm0 before end-barrier q-1;
// slot-q data guaranteed by vmcnt(8)+barrier at end of q-1; STAGE(q+4)
// (overwrites slot q) can only issue after all waves pass end-barrier q.
template<int CBF>
__global__ __launch_bounds__(512) void gemm_big(const u16* __restrict__ A,
                                                const u16* __restrict__ W,
                                                const float* __restrict__ bias,
                                                void* __restrict__ Cv,
                                                int M, int N, int K, int lda, int ldc) {
    __shared__ u16 lds[65536];   // 4 slots x 16384 u16

    int nwgx = gridDim.x;
    int nwg = nwgx * gridDim.y;
    int bid = blockIdx.y * nwgx + blockIdx.x;
    int cpx = nwg >> 3;                        // grids here always %8==0
    bid = (bid & 7) * cpx + (bid >> 3);
    int bm = (bid / nwgx) * 256;
    int bn = (bid % nwgx) * 256;

    int tid = threadIdx.x, wid = tid >> 6, lane = tid & 63;
    int wm = wid >> 2, wn = wid & 3;           // 2 x 4 wave grid
    int lr = lane & 15, g = lane >> 4;

    // ---- staging source (per lane): line pr, slot s; logical = s ^ (pr&7) ----
    int prl = lane >> 3, slot = lane & 7;
    const u16 *sA0, *sA1, *sB0, *sB1;
    {
        int pr0 = wid * 16 + prl;
        int gl0 = slot ^ (pr0 & 7);
        int row0 = 2 * pr0 + (gl0 >> 2);
        int co0 = (gl0 & 3) << 3;
        sA0 = A + (size_t)(bm + row0) * lda + co0;
        sB0 = W + (size_t)(bn + row0) * (size_t)K + co0;
        int pr1 = wid * 16 + 8 + prl;
        int gl1 = slot ^ (pr1 & 7);
        int row1 = 2 * pr1 + (gl1 >> 2);
        int co1 = (gl1 & 3) << 3;
        sA1 = A + (size_t)(bm + row1) * lda + co1;
        sB1 = W + (size_t)(bn + row1) * (size_t)K + co1;
    }

    // ---- fragment read offsets (per lane, u16 units) ----
    int slt = (((lane & 1) << 2) | g) ^ ((lr >> 1) & 7);   // physical slot-of-8
    int laneA = (wm * 64 + (lr >> 1)) * 64 + (slt << 3);          // + m*512
    int laneB = 8192 + (wn * 32 + (lr >> 1)) * 64 + (slt << 3);   // + n*512

#define GL_(srcp, dstofs) __builtin_amdgcn_global_load_lds( \
        (const __attribute__((address_space(1))) void*)(srcp), \
        (__attribute__((address_space(3))) void*)(&lds[dstofs]), 16, 0, 0)

    // stage data for global phase p into slot p&3 (4 loads/wave)
#define STAGE_(p) { \
        size_t ko_ = (size_t)((p) >> 1) * 64 + ((p) & 1) * 32; \
        int rg_ = ((p) & 3) * 16384; \
        GL_(sA0 + ko_, rg_ + (wid * 16) * 64); \
        GL_(sB0 + ko_, rg_ + 8192 + (wid * 16) * 64); \
        GL_(sA1 + ko_, rg_ + (wid * 16 + 8) * 64); \
        GL_(sB1 + ko_, rg_ + 8192 + (wid * 16 + 8) * 64); \
    }

    f32x4 acc[8][4];
    #pragma unroll
    for (int m = 0; m < 8; ++m)
        #pragma unroll
        for (int n = 0; n < 4; ++n) acc[m][n] = (f32x4){0.f, 0.f, 0.f, 0.f};

    int nph = K >> 5;   // 2*nt phases

    // prologue: stage phases 0,1,2; wait phase-0 data (groups 1,2 outstanding)
    STAGE_(0); STAGE_(1); STAGE_(2);
    asm volatile("s_waitcnt vmcnt(8)" ::: "memory");
    __builtin_amdgcn_s_barrier();
    __builtin_amdgcn_sched_barrier(0);

    for (int q = 0; q < nph; ++q) {
        int ho = (q & 3) * 16384;
        bf16x8 af[8], bfr[4];
        #pragma unroll
        for (int n = 0; n < 4; ++n)
            bfr[n] = *(bf16x8*)&lds[ho + laneB + n * 512];
        #pragma unroll
        for (int m = 0; m < 8; ++m)
            af[m] = *(bf16x8*)&lds[ho + laneA + m * 512];
        // prefetch 3 phases ahead into the slot freed by phase q-1
        if (q + 3 < nph) STAGE_(q + 3);
        // wait only OWN reads; no mid-barrier -> waves drift (LDS || MFMA overlap)
        asm volatile("s_waitcnt lgkmcnt(0)" ::: "memory");
        __builtin_amdgcn_sched_barrier(0);
        __builtin_amdgcn_s_setprio(1);
        #pragma unroll
        for (int m = 0; m < 8; ++m)
            #pragma unroll
            for (int n = 0; n < 4; ++n)
                acc[m][n] = __builtin_amdgcn_mfma_f32_16x16x32_bf16(af[m], bfr[n], acc[m][n], 0, 0, 0);
        __builtin_amdgcn_s_setprio(0);
        __builtin_amdgcn_sched_barrier(0);
        if (q + 1 < nph) {
            // ensure slot (q+1)&3's data (staged at q-2) retired; keep newer in flight
            if (q + 4 <= nph)      { asm volatile("s_waitcnt vmcnt(8)" ::: "memory"); }
            else if (q + 3 == nph) { asm volatile("s_waitcnt vmcnt(4)" ::: "memory"); }
            else                   { asm volatile("s_waitcnt vmcnt(0)" ::: "memory"); }
            __builtin_amdgcn_s_barrier();
            __builtin_amdgcn_sched_barrier(0);
        }
    }
#undef STAGE_
#undef GL_

    if constexpr (CBF) {
        // LDS-transpose epilogue: per-wave scratch [64][80] u16 at wid*5120
        // (max 40960 < 49152 = slot 3). Barrier first: all waves' loop ds_reads
        // completed (per-wave lgkm0 before their final MFMA).
        __builtin_amdgcn_s_barrier();
        u16* scr = &lds[wid * 5120];
        float bv[4];
        #pragma unroll
        for (int n = 0; n < 4; ++n)
            bv[n] = bias ? bias[bn + wn * 64 + n * 16 + lr] : 0.f;
        int l8r = lane >> 3, l8c = lane & 7;
        #pragma unroll
        for (int grp = 0; grp < 2; ++grp) {
            #pragma unroll
            for (int m2 = 0; m2 < 4; ++m2) {
                #pragma unroll
                for (int n = 0; n < 4; ++n) {
                    #pragma unroll
                    for (int j = 0; j < 4; ++j) {
                        int rl = m2 * 16 + g * 4 + j;
                        scr[rl * 80 + n * 16 + lr] = f2b(acc[grp * 4 + m2][n][j] + bv[n]);
                    }
                }
            }
            asm volatile("s_waitcnt lgkmcnt(0)" ::: "memory");
            #pragma unroll
            for (int it = 0; it < 8; ++it) {
                int rl = it * 8 + l8r;
                uint4 v = *(uint4*)&scr[rl * 80 + l8c * 8];
                int row = bm + wm * 128 + grp * 64 + rl;
                int col = bn + wn * 64 + l8c * 8;
                if (col < N)
                    *(uint4*)((u16*)Cv + (size_t)row * ldc + col) = v;
            }
        }
    } else {
        int crow = bm + wm * 128 + (g << 2);
        int ccol = bn + wn * 64 + lr;
        #pragma unroll
        for (int n = 0; n < 4; ++n) {
            int col = ccol + n * 16;
            if (col < N) {
                float bv = bias ? bias[col] : 0.f;
                #pragma unroll
                for (int m = 0; m < 8; ++m) {
                    #pragma unroll
                    for (int j = 0; j < 4; ++j) {
                        int row = crow + m * 16 + j;
                        ((float*)Cv)[(size_t)row * ldc + col] = acc[m][n][j] + bv;
                    }
                }
            }
        }
    }
}

// ---------- LayerNorm (in place on bf16 u), vectorized ----------
__global__ __launch_bounds__(256) void layernorm_k(u16* __restrict__ u,
                                                   const float* __restrict__ g,
                                                   const float* __restrict__ bt) {
    int row = blockIdx.x, t = threadIdx.x;
    u16* p = u + (size_t)row * D_MODELx;
    ushort4 v4 = *(ushort4*)(p + t * 4);
    float v[4] = {b2f(v4.x), b2f(v4.y), b2f(v4.z), b2f(v4.w)};
    float s = v[0] + v[1] + v[2] + v[3];
    float mean = block_sum(s) * (1.f / D_MODELx);
    float vs = 0.f;
    #pragma unroll
    for (int i = 0; i < 4; ++i) { float d = v[i] - mean; vs += d * d; }
    float var = block_sum(vs) * (1.f / D_MODELx);
    float inv = rsqrtf(var + 1e-5f);
    ushort4 o;
    o.x = f2b((v[0] - mean) * inv * g[t * 4 + 0] + bt[t * 4 + 0]);
    o.y = f2b((v[1] - mean) * inv * g[t * 4 + 1] + bt[t * 4 + 1]);
    o.z = f2b((v[2] - mean) * inv * g[t * 4 + 2] + bt[t * 4 + 2]);
    o.w = f2b((v[3] - mean) * inv * g[t * 4 + 3] + bt[t * 4 + 3]);
    *(ushort4*)(p + t * 4) = o;
}

// ---------- dt softplus + per-chunk cumsum: one wave per (b,h,c) ----------
__global__ __launch_bounds__(256) void dt_acs_k(const u16* __restrict__ xb,
                                                const float* __restrict__ dt_bias,
                                                const float* __restrict__ A_log,
                                                float* __restrict__ dtv, float* __restrict__ acs) {
    int gid = blockIdx.x * 4 + (threadIdx.x >> 6);
    int lane = threadIdx.x & 63;
    int c = gid & 31;
    int h = (gid >> 5) & 31;
    int b = gid >> 10;
    float A = -expf(A_log[h]);
    int row = b * LSEQ + c * CHUNKx + lane;
    float x = b2f(xb[(size_t)row * LDX + XB_DT + h]) + dt_bias[h];
    float d = (x > 20.f) ? x : log1pf(expf(x));
    dtv[(size_t)row * NHEADSx + h] = d;
    float v = A * d;
    #pragma unroll
    for (int off = 1; off < 64; off <<= 1) {
        float t = __shfl_up(v, off);
        if (lane >= off) v += t;
    }
    acs[(((size_t)(b * NHEADSx + h)) * NCHUNKx + c) * CHUNKx + lane] = v;
}

// ---------- causal depthwise conv (k=4) + SiLU, in place, 8-ch vectorized ----------
__global__ __launch_bounds__(256) void conv_k(u16* __restrict__ xb,
                                              const float* __restrict__ w,
                                              const float* __restrict__ bias) {
    int chgl = threadIdx.x & 3, seg = threadIdx.x >> 2;
    int ch0 = (blockIdx.x * 4 + chgl) * 8;
    int b = blockIdx.y;
    float4 wv[8];
    float bs[8];
    #pragma unroll
    for (int j = 0; j < 8; ++j) wv[j] = *(const float4*)(w + (size_t)(ch0 + j) * 4);
    #pragma unroll
    for (int j = 0; j < 8; ++j) bs[j] = bias[ch0 + j];
    size_t base = ((size_t)b * LSEQ + seg * 32) * LDX + ch0;
    float h0[8] = {}, h1[8] = {}, h2[8] = {};
    if (seg) {
        up8(*(const uint4*)(xb + base - 3 * (size_t)LDX), h0);
        up8(*(const uint4*)(xb + base - 2 * (size_t)LDX), h1);
        up8(*(const uint4*)(xb + base - 1 * (size_t)LDX), h2);
    }
    __syncthreads();
    for (int i = 0; i < 32; ++i) {
        float xl[8], o[8];
        up8(*(const uint4*)(xb + base + (size_t)i * LDX), xl);
        #pragma unroll
        for (int j = 0; j < 8; ++j) {
            float v = fmaf(wv[j].w, xl[j], fmaf(wv[j].z, h2[j],
                      fmaf(wv[j].y, h1[j], fmaf(wv[j].x, h0[j], bs[j]))));
            o[j] = silu_f(v);
            h0[j] = h1[j]; h1[j] = h2[j]; h2[j] = xl[j];
        }
        *(uint4*)(xb + base + (size_t)i * LDX) = pk8(o);
    }
}

// ---------- fused SSD v3 (round-6 proven version) ----------
__global__ __launch_bounds__(512) void ssd_k(u16* __restrict__ xb,
                                             const float* __restrict__ dtv,
                                             const float* __restrict__ acs,
                                             const float* __restrict__ Dp) {
    __shared__ u16 Xt[64 * 72];
    __shared__ u16 Bl[64 * 136];
    __shared__ u16 Bt[128 * 72];
    __shared__ u16 Cl[64 * 136];
    __shared__ u16 Gp[64 * 72];
    __shared__ u16 Sp[64 * 136];
    __shared__ float acss[64], eaS[64], dtS[64], ddS[64];
    __shared__ float dcS;

    int h = blockIdx.x, b = blockIdx.y;
    int tid = threadIdx.x;
    int w = tid >> 6, lane = tid & 63, l15 = lane & 15, g = lane >> 4;
    int lt = w >> 1, hf = w & 1;
    float Dh = Dp[h];

    int sr = tid >> 3, scq = tid & 7;
    int srh = sr >> 3, srl = sr & 7;
    int sgrp = ((srh ^ scq) << 3) + srl;

    f32x4 sreg[4];
    #pragma unroll
    for (int pt = 0; pt < 4; ++pt) sreg[pt] = (f32x4){0.f, 0.f, 0.f, 0.f};

    const float* acb = acs + ((size_t)(b * NHEADSx + h)) * NCHUNKx * CHUNKx;

    for (int i = tid; i < 64 * 136 / 8; i += 512) ((uint4*)Sp)[i] = (uint4){0, 0, 0, 0};

    if (tid < 64) {
        float a = acb[tid];
        float a63 = __shfl(a, 63);
        float d = dtv[(size_t)(b * LSEQ + tid) * NHEADSx + h];
        acss[tid] = a; eaS[tid] = __expf(a); dtS[tid] = d;
        ddS[tid] = d * __expf(a63 - a);
        if (tid == 0) dcS = __expf(a63);
    }
    uint4 rXs, rB0, rB1, rC0, rC1;
    {
        size_t rowb = ((size_t)(b * LSEQ) + sr) * LDX;
        rXs = *(const uint4*)(xb + rowb + h * 64 + scq * 8);
        rB0 = *(const uint4*)(xb + rowb + XB_B + scq * 8);
        rB1 = *(const uint4*)(xb + rowb + XB_B + 64 + scq * 8);
        rC0 = *(const uint4*)(xb + rowb + XB_C + scq * 8);
        rC1 = *(const uint4*)(xb + rowb + XB_C + 64 + scq * 8);
    }
    __syncthreads();
    {
        *(uint4*)&Bl[sr * 136 + scq * 8] = rB0;
        *(uint4*)&Bl[sr * 136 + 64 + scq * 8] = rB1;
        *(uint4*)&Cl[sr * 136 + scq * 8] = rC0;
        *(uint4*)&Cl[sr * 136 + 64 + scq * 8] = rC1;
        const u16* px = (const u16*)&rXs;
        const u16* pb0 = (const u16*)&rB0;
        const u16* pb1 = (const u16*)&rB1;
        float dd = ddS[sr];
        #pragma unroll
        for (int j = 0; j < 8; ++j) {
            Xt[(scq * 8 + j) * 72 + sgrp] = px[j];
            Bt[(scq * 8 + j) * 72 + sgrp] = f2b(b2f(pb0[j]) * dd);
            Bt[(64 + scq * 8 + j) * 72 + sgrp] = f2b(b2f(pb1[j]) * dd);
        }
    }
    __syncthreads();

    for (int c = 0; c < NCHUNKx; ++c) {
        int row0 = b * LSEQ + c * CHUNKx;
        if (c + 1 < NCHUNKx) {
            size_t rowb = ((size_t)row0 + CHUNKx + sr) * LDX;
            rXs = *(const uint4*)(xb + rowb + h * 64 + scq * 8);
            rB0 = *(const uint4*)(xb + rowb + XB_B + scq * 8);
            rB1 = *(const uint4*)(xb + rowb + XB_B + 64 + scq * 8);
            rC0 = *(const uint4*)(xb + rowb + XB_C + scq * 8);
            rC1 = *(const uint4*)(xb + rowb + XB_C + 64 + scq * 8);
        }
        f32x4 accG[2], yac[2];
        accG[0] = (f32x4){0.f, 0.f, 0.f, 0.f}; accG[1] = (f32x4){0.f, 0.f, 0.f, 0.f};
        yac[0] = (f32x4){0.f, 0.f, 0.f, 0.f};  yac[1] = (f32x4){0.f, 0.f, 0.f, 0.f};
        #pragma unroll
        for (int kk = 0; kk < 4; ++kk) {
            bf16x8 aC = *(bf16x8*)&Cl[(16 * lt + l15) * 136 + 32 * kk + 8 * g];
            #pragma unroll
            for (int q = 0; q < 2; ++q) {
                int st = 16 * (2 * hf + q) + l15;
                bf16x8 bB = *(bf16x8*)&Bl[st * 136 + 32 * kk + 8 * g];
                accG[q] = __builtin_amdgcn_mfma_f32_16x16x32_bf16(aC, bB, accG[q], 0, 0, 0);
                bf16x8 bS = *(bf16x8*)&Sp[st * 136 + 32 * kk + 8 * g];
                yac[q] = __builtin_amdgcn_mfma_f32_16x16x32_bf16(aC, bS, yac[q], 0, 0, 0);
            }
        }
        float dc = dcS;
        #pragma unroll
        for (int q = 0; q < 2; ++q) {
            int s = 16 * (2 * hf + q) + l15;
            float as = acss[s], ds = dtS[s];
            #pragma unroll
            for (int j = 0; j < 4; ++j) {
                int l = 16 * lt + 4 * g + j;
                yac[q][j] *= eaS[l];
                float v = (s <= l) ? accG[q][j] * __expf(acss[l] - as) * ds : 0.f;
                Gp[l * 72 + s] = f2b(v);
            }
        }
        #pragma unroll
        for (int pt = 0; pt < 4; ++pt)
            #pragma unroll
            for (int j = 0; j < 4; ++j) sreg[pt][j] *= dc;
        __syncthreads();

        #pragma unroll
        for (int kk = 0; kk < 2; ++kk) {
            bf16x8 aG = *(bf16x8*)&Gp[(16 * lt + l15) * 72 + 32 * kk + 8 * g];
            #pragma unroll
            for (int q = 0; q < 2; ++q) {
                int row = 16 * (2 * hf + q) + l15;
                int grp = (4 * kk + g) ^ ((row >> 3) & 7);
                bf16x8 bXq = *(bf16x8*)&Xt[row * 72 + grp * 8];
                yac[q] = __builtin_amdgcn_mfma_f32_16x16x32_bf16(aG, bXq, yac[q], 0, 0, 0);
            }
            int rowb = 16 * w + l15;
            int grpb = (4 * kk + g) ^ ((rowb >> 3) & 7);
            bf16x8 aB = *(bf16x8*)&Bt[rowb * 72 + grpb * 8];
            #pragma unroll
            for (int pt = 0; pt < 4; ++pt) {
                int row = 16 * pt + l15;
                int grp = (4 * kk + g) ^ ((row >> 3) & 7);
                bf16x8 bX = *(bf16x8*)&Xt[row * 72 + grp * 8];
                sreg[pt] = __builtin_amdgcn_mfma_f32_16x16x32_bf16(aB, bX, sreg[pt], 0, 0, 0);
            }
        }
        #pragma unroll
        for (int q = 0; q < 2; ++q) {
            int p = 16 * (2 * hf + q) + l15;
            int ph = (p >> 3) & 7;
            #pragma unroll
            for (int j = 0; j < 4; ++j) {
                int l = 16 * lt + 4 * g + j;
                int col = (((l >> 3) ^ ph) << 3) + (l & 7);
                float xsv = b2f(Xt[p * 72 + col]);
                xb[(size_t)(row0 + l) * LDX + h * 64 + p] = f2b(yac[q][j] + Dh * xsv);
            }
        }
        if (tid < 64 && c + 1 < NCHUNKx) {
            float a = acb[(c + 1) * CHUNKx + tid];
            float a63 = __shfl(a, 63);
            float d = dtv[(size_t)(row0 + CHUNKx + tid) * NHEADSx + h];
            acss[tid] = a; eaS[tid] = __expf(a); dtS[tid] = d;
            ddS[tid] = d * __expf(a63 - a);
            if (tid == 0) dcS = __expf(a63);
        }
        __syncthreads();
        #pragma unroll
        for (int pt = 0; pt < 4; ++pt) {
            ushort4 pk;
            pk.x = f2b(sreg[pt][0]); pk.y = f2b(sreg[pt][1]);
            pk.z = f2b(sreg[pt][2]); pk.w = f2b(sreg[pt][3]);
            *(ushort4*)&Sp[(16 * pt + l15) * 136 + 16 * w + 4 * g] = pk;
        }
        if (c + 1 < NCHUNKx) {
            *(uint4*)&Bl[sr * 136 + scq * 8] = rB0;
            *(uint4*)&Bl[sr * 136 + 64 + scq * 8] = rB1;
            *(uint4*)&Cl[sr * 136 + scq * 8] = rC0;
            *(uint4*)&Cl[sr * 136 + 64 + scq * 8] = rC1;
            const u16* px = (const u16*)&rXs;
            const u16* pb0 = (const u16*)&rB0;
            const u16* pb1 = (const u16*)&rB1;
            float dd = ddS[sr];
            #pragma unroll
            for (int j = 0; j < 8; ++j) {
                Xt[(scq * 8 + j) * 72 + sgrp] = px[j];
                Bt[(scq * 8 + j) * 72 + sgrp] = f2b(b2f(pb0[j]) * dd);
                Bt[(64 + scq * 8 + j) * 72 + sgrp] = f2b(b2f(pb1[j]) * dd);
            }
        }
        __syncthreads();
    }
}

// ---------- gated RMSNorm in place over y, vectorized ----------
__global__ __launch_bounds__(256) void rmsgate_k(u16* __restrict__ xb,
                                                 const u16* __restrict__ zb,
                                                 const float* __restrict__ w) {
    int row = blockIdx.x, t = threadIdx.x;
    const u16* zp = zb + (size_t)row * D_INNERx;
    u16* yp = xb + (size_t)row * LDX;
    float zf[8], yf[8], vals[8];
    up8(*(const uint4*)(zp + t * 8), zf);
    up8(*(const uint4*)(yp + t * 8), yf);
    float ss = 0.f;
    #pragma unroll
    for (int i = 0; i < 8; ++i) {
        float y = yf[i] * silu_f(zf[i]);
        vals[i] = y; ss += y * y;
    }
    float tot = block_sum(ss);
    float scale = rsqrtf(tot * (1.f / D_INNERx) + 1e-5f);
    #pragma unroll
    for (int i = 0; i < 8; ++i) vals[i] *= scale * w[t * 8 + i];
    *(uint4*)(yp + t * 8) = pk8(vals);
}

// ---------- hidden = out[:, -1, :] ----------
__global__ void hidden_k(float* __restrict__ out) {
    int i = blockIdx.x * blockDim.x + threadIdx.x;
    int b = i >> 10, d = i & 1023;
    out[(size_t)NTOK * D_MODELx + i] = out[((size_t)(b * LSEQ + LSEQ - 1)) * D_MODELx + d];
}

extern "C" void kernel_launch(void* const* d_in, const int* in_sizes, int n_in,
                              void* d_out, int out_size, void* d_ws, size_t ws_size,
                              hipStream_t stream) {
    const float* x       = (const float*)d_in[0];
    const float* Wi      = (const float*)d_in[1];
    const float* bi      = (const float*)d_in[2];
    const float* ln_g    = (const float*)d_in[3];
    const float* ln_b    = (const float*)d_in[4];
    const float* Win     = (const float*)d_in[5];
    const float* conv_w  = (const float*)d_in[6];
    const float* conv_b  = (const float*)d_in[7];
    const float* dt_bias = (const float*)d_in[8];
    const float* A_log   = (const float*)d_in[9];
    const float* Dv      = (const float*)d_in[10];
    const float* rms_w   = (const float*)d_in[11];
    const float* Wout    = (const float*)d_in[12];
    float* out = (float*)d_out;

    if (ws_size < 118489088ull) return;
    u16* xb  = (u16*)d_ws;                                   // [NTOK][LDX] bf16
    u16* ub  = xb + (size_t)NTOK * LDX;                      // [NTOK][1024] bf16
    u16* Woutb = ub;                                         // overlay after y ready
    u16* Rb  = ub + (size_t)NTOK * D_MODELx;                 // 8 MiB region
    u16* Wib  = Rb;                                          // 1024x1024
    u16* Winb = Rb + (size_t)1024 * 1024;                    // up to 2560x1024 (padded)
    float* acs = (float*)Rb;                                 // overlays Wib/Winb after GEMMs
    float* dtv = acs + (size_t)B_N * NHEADSx * NCHUNKx * CHUNKx;
    u16* xbf = xb;
    u16* zb  = (u16*)d_out;

    // 0. conversions
    cvt_f2b_k<<<16384, 256, 0, stream>>>(x, xbf, 16777216 / 4);
    cvt_f2b_k<<<1024, 256, 0, stream>>>(Wi, Wib, 1048576 / 4);
    // 1. u = x @ Wi^T + bi
    gemm_big<1><<<dim3(4, 64), 512, 0, stream>>>(
        xbf, Wib, bi, ub, NTOK, D_MODELx, D_INx, D_INx, D_MODELx);
    // 2. LayerNorm
    layernorm_k<<<NTOK, 256, 0, stream>>>(ub, ln_g, ln_b);
    // 3a. z = u @ Win[0:2048]^T -> d_out
    cvt_f2b_k<<<2048, 256, 0, stream>>>(Win, Winb, (2048 * 1024) / 4);
    gemm_big<1><<<dim3(8, 64), 512, 0, stream>>>(
        ub, Winb, nullptr, zb, NTOK, D_INNERx, D_MODELx, D_MODELx, D_INNERx);
    // 3b. xBCdt = u @ Win[2048:4384]^T -> xb  (N=2336 ragged; Winb padded to 2560 rows)
    cvt_f2b_k<<<2336, 256, 0, stream>>>(Win + (size_t)2048 * 1024, Winb, (2336 * 1024) / 4);
    gemm_big<1><<<dim3(10, 64), 512, 0, stream>>>(
        ub, Winb, nullptr, xb, NTOK, LDX, D_MODELx, D_MODELx, LDX);
    // 4. dt + per-chunk cumsum (wave-parallel scan)
    dt_acs_k<<<2048, 256, 0, stream>>>(xb, dt_bias, A_log, dtv, acs);
    // 5. conv + silu in place (8-ch vectorized, 576 blocks)
    conv_k<<<dim3(CONV_DIMx / 32, B_N), 256, 0, stream>>>(xb, conv_w, conv_b);
    // 6+7. fused SSD v3
    ssd_k<<<dim3(NHEADSx, B_N), 512, 0, stream>>>(xb, dtv, acs, Dv);
    // 8. gated RMSNorm in place over y
    rmsgate_k<<<NTOK, 256, 0, stream>>>(xb, zb, rms_w);
    // 9. out = yn @ Wout^T
    cvt_f2b_k<<<2048, 256, 0, stream>>>(Wout, Woutb, (2048 * 1024) / 4);
    gemm_big<0><<<dim3(4, 64), 512, 0, stream>>>(
        xb, Woutb, nullptr, out, NTOK, D_MODELx, D_INNERx, LDX, D_MODELx);
    // 10. hidden
    hidden_k<<<(B_N * D_MODELx) / 256, 256, 0, stream>>>(out);
}

// Round 16
// 540.258 us; speedup vs baseline: 1.0113x; 1.0113x over previous
//
#include <hip/hip_runtime.h>
#include <math.h>

typedef unsigned short u16;
typedef __attribute__((ext_vector_type(8))) short bf16x8;
typedef __attribute__((ext_vector_type(4))) float f32x4;

#define B_N 8
#define LSEQ 2048
#define D_INx 1024
#define D_MODELx 1024
#define D_STATEx 128
#define D_INNERx 2048
#define NHEADSx 32
#define HEADDIMx 64
#define CONV_DIMx 2304
#define D_IN_PROJx 4384
#define CHUNKx 64
#define NCHUNKx 32
#define NTOK (B_N*LSEQ)   // 16384

#define LDX 2336
#define XB_B 2048
#define XB_C 2176
#define XB_DT 2304

// ---------- bf16 helpers (storage only; math fp32) ----------
__device__ __forceinline__ float b2f(u16 u) {
    return __uint_as_float(((unsigned)u) << 16);
}
__device__ __forceinline__ u16 f2b(float f) {
    unsigned u = __float_as_uint(f);
    return (u16)((u + 0x7FFFu + ((u >> 16) & 1u)) >> 16);  // RNE
}
__device__ __forceinline__ void up8(uint4 v, float* f) {
    f[0] = b2f((u16)(v.x & 0xffff)); f[1] = b2f((u16)(v.x >> 16));
    f[2] = b2f((u16)(v.y & 0xffff)); f[3] = b2f((u16)(v.y >> 16));
    f[4] = b2f((u16)(v.z & 0xffff)); f[5] = b2f((u16)(v.z >> 16));
    f[6] = b2f((u16)(v.w & 0xffff)); f[7] = b2f((u16)(v.w >> 16));
}
__device__ __forceinline__ uint4 pk8(const float* f) {
    uint4 v;
    v.x = (unsigned)f2b(f[0]) | ((unsigned)f2b(f[1]) << 16);
    v.y = (unsigned)f2b(f[2]) | ((unsigned)f2b(f[3]) << 16);
    v.z = (unsigned)f2b(f[4]) | ((unsigned)f2b(f[5]) << 16);
    v.w = (unsigned)f2b(f[6]) | ((unsigned)f2b(f[7]) << 16);
    return v;
}

__device__ __forceinline__ float block_sum(float v) {
    __shared__ float sm[8];
    int lane = threadIdx.x & 63, wid = threadIdx.x >> 6;
    #pragma unroll
    for (int o = 32; o; o >>= 1) v += __shfl_xor(v, o);
    __syncthreads();
    if (lane == 0) sm[wid] = v;
    __syncthreads();
    float r = 0.f;
    int nw = blockDim.x >> 6;
    for (int w = 0; w < nw; ++w) r += sm[w];
    return r;
}

__device__ __forceinline__ float silu_f(float x) {
    return x / (1.f + expf(-x));
}

// ---------- fp32 -> bf16 conversion ----------
__global__ __launch_bounds__(256) void cvt_f2b_k(const float* __restrict__ in,
                                                 u16* __restrict__ out, int n4) {
    int i = blockIdx.x * 256 + threadIdx.x;
    if (i >= n4) return;
    float4 v = ((const float4*)in)[i];
    ushort4 o;
    o.x = f2b(v.x); o.y = f2b(v.y); o.z = f2b(v.z); o.w = f2b(v.w);
    ((ushort4*)out)[i] = o;
}

// ---------- bf16 MFMA GEMM v8 (round-14 proven best): ring-4, 16-MFMA sub-phases,
// LDS-transpose bf16 epilogue. C[M,N] = A[M,K] @ W[N,K]^T (+bias). M%256==0, K%128==0.
template<int CBF>
__global__ __launch_bounds__(512) void gemm_big(const u16* __restrict__ A,
                                                const u16* __restrict__ W,
                                                const float* __restrict__ bias,
                                                void* __restrict__ Cv,
                                                int M, int N, int K, int lda, int ldc) {
    __shared__ u16 lds[65536];   // 4 slots x 16384 u16

    int nwgx = gridDim.x;
    int nwg = nwgx * gridDim.y;
    int bid = blockIdx.y * nwgx + blockIdx.x;
    int cpx = nwg >> 3;                        // grids here always %8==0
    bid = (bid & 7) * cpx + (bid >> 3);
    int bm = (bid / nwgx) * 256;
    int bn = (bid % nwgx) * 256;

    int tid = threadIdx.x, wid = tid >> 6, lane = tid & 63;
    int wm = wid >> 2, wn = wid & 3;           // 2 x 4 wave grid
    int lr = lane & 15, g = lane >> 4;

    // ---- staging source (per lane): line pr, slot s; logical = s ^ (pr&7) ----
    int prl = lane >> 3, slot = lane & 7;
    const u16 *sA0, *sA1, *sB0, *sB1;
    {
        int pr0 = wid * 16 + prl;
        int gl0 = slot ^ (pr0 & 7);
        int row0 = 2 * pr0 + (gl0 >> 2);
        int co0 = (gl0 & 3) << 3;
        sA0 = A + (size_t)(bm + row0) * lda + co0;
        sB0 = W + (size_t)(bn + row0) * (size_t)K + co0;
        int pr1 = wid * 16 + 8 + prl;
        int gl1 = slot ^ (pr1 & 7);
        int row1 = 2 * pr1 + (gl1 >> 2);
        int co1 = (gl1 & 3) << 3;
        sA1 = A + (size_t)(bm + row1) * lda + co1;
        sB1 = W + (size_t)(bn + row1) * (size_t)K + co1;
    }

    // ---- fragment read offsets (per lane, u16 units) ----
    int slt = (((lane & 1) << 2) | g) ^ ((lr >> 1) & 7);   // physical slot-of-8
    int laneA = (wm * 64 + (lr >> 1)) * 64 + (slt << 3);          // + m*512
    int laneB = 8192 + (wn * 32 + (lr >> 1)) * 64 + (slt << 3);   // + n*512

#define GL_(srcp, dstofs) __builtin_amdgcn_global_load_lds( \
        (const __attribute__((address_space(1))) void*)(srcp), \
        (__attribute__((address_space(3))) void*)(&lds[dstofs]), 16, 0, 0)

    // stage data for global phase p into slot p&3 (4 loads/wave)
#define STAGE_(p) { \
        size_t ko_ = (size_t)((p) >> 1) * 64 + ((p) & 1) * 32; \
        int rg_ = ((p) & 3) * 16384; \
        GL_(sA0 + ko_, rg_ + (wid * 16) * 64); \
        GL_(sB0 + ko_, rg_ + 8192 + (wid * 16) * 64); \
        GL_(sA1 + ko_, rg_ + (wid * 16 + 8) * 64); \
        GL_(sB1 + ko_, rg_ + 8192 + (wid * 16 + 8) * 64); \
    }

    f32x4 acc[8][4];
    #pragma unroll
    for (int m = 0; m < 8; ++m)
        #pragma unroll
        for (int n = 0; n < 4; ++n) acc[m][n] = (f32x4){0.f, 0.f, 0.f, 0.f};

    int nph = K >> 5;   // 2*nt phases

    // prologue: stage phases 0,1,2; wait phase-0 data (groups 1,2 outstanding)
    STAGE_(0); STAGE_(1); STAGE_(2);
    asm volatile("s_waitcnt vmcnt(8)" ::: "memory");
    __builtin_amdgcn_s_barrier();
    __builtin_amdgcn_sched_barrier(0);

    for (int q = 0; q < nph; ++q) {
        int ho = (q & 3) * 16384;
        // ---- sub-phase A: af + first two B fragments ----
        bf16x8 af[8], bfr0, bfr1, bfr2, bfr3;
        #pragma unroll
        for (int m = 0; m < 8; ++m)
            af[m] = *(bf16x8*)&lds[ho + laneA + m * 512];
        bfr0 = *(bf16x8*)&lds[ho + laneB + 0 * 512];
        bfr1 = *(bf16x8*)&lds[ho + laneB + 1 * 512];
        if (q + 3 < nph) STAGE_(q + 3);
        __builtin_amdgcn_sched_barrier(0);
        __builtin_amdgcn_s_barrier();
        asm volatile("s_waitcnt lgkmcnt(0)" ::: "memory");
        __builtin_amdgcn_sched_barrier(0);
        __builtin_amdgcn_s_setprio(1);
        #pragma unroll
        for (int m = 0; m < 8; ++m)
            acc[m][0] = __builtin_amdgcn_mfma_f32_16x16x32_bf16(af[m], bfr0, acc[m][0], 0, 0, 0);
        #pragma unroll
        for (int m = 0; m < 8; ++m)
            acc[m][1] = __builtin_amdgcn_mfma_f32_16x16x32_bf16(af[m], bfr1, acc[m][1], 0, 0, 0);
        __builtin_amdgcn_s_setprio(0);
        // ---- sub-phase B: last two B fragments ----
        bfr2 = *(bf16x8*)&lds[ho + laneB + 2 * 512];
        bfr3 = *(bf16x8*)&lds[ho + laneB + 3 * 512];
        __builtin_amdgcn_sched_barrier(0);
        __builtin_amdgcn_s_barrier();
        asm volatile("s_waitcnt lgkmcnt(0)" ::: "memory");
        __builtin_amdgcn_sched_barrier(0);
        __builtin_amdgcn_s_setprio(1);
        #pragma unroll
        for (int m = 0; m < 8; ++m)
            acc[m][2] = __builtin_amdgcn_mfma_f32_16x16x32_bf16(af[m], bfr2, acc[m][2], 0, 0, 0);
        #pragma unroll
        for (int m = 0; m < 8; ++m)
            acc[m][3] = __builtin_amdgcn_mfma_f32_16x16x32_bf16(af[m], bfr3, acc[m][3], 0, 0, 0);
        __builtin_amdgcn_s_setprio(0);
        __builtin_amdgcn_sched_barrier(0);
        if (q + 1 < nph) {
            if (q + 4 <= nph)      { asm volatile("s_waitcnt vmcnt(8)" ::: "memory"); }
            else if (q + 3 == nph) { asm volatile("s_waitcnt vmcnt(4)" ::: "memory"); }
            else                   { asm volatile("s_waitcnt vmcnt(0)" ::: "memory"); }
            __builtin_amdgcn_s_barrier();
            __builtin_amdgcn_sched_barrier(0);
        }
    }
#undef STAGE_
#undef GL_

    if constexpr (CBF) {
        // LDS-transpose epilogue: per-wave scratch [64][80] u16 at wid*5120
        // (max 40960 < 49152 = slot 3, which holds the final phase's operands).
        __builtin_amdgcn_s_barrier();
        u16* scr = &lds[wid * 5120];
        float bv[4];
        #pragma unroll
        for (int n = 0; n < 4; ++n)
            bv[n] = bias ? bias[bn + wn * 64 + n * 16 + lr] : 0.f;
        int l8r = lane >> 3, l8c = lane & 7;
        #pragma unroll
        for (int grp = 0; grp < 2; ++grp) {
            #pragma unroll
            for (int m2 = 0; m2 < 4; ++m2) {
                #pragma unroll
                for (int n = 0; n < 4; ++n) {
                    #pragma unroll
                    for (int j = 0; j < 4; ++j) {
                        int rl = m2 * 16 + g * 4 + j;
                        scr[rl * 80 + n * 16 + lr] = f2b(acc[grp * 4 + m2][n][j] + bv[n]);
                    }
                }
            }
            asm volatile("s_waitcnt lgkmcnt(0)" ::: "memory");
            #pragma unroll
            for (int it = 0; it < 8; ++it) {
                int rl = it * 8 + l8r;
                uint4 v = *(uint4*)&scr[rl * 80 + l8c * 8];
                int row = bm + wm * 128 + grp * 64 + rl;
                int col = bn + wn * 64 + l8c * 8;
                if (col < N)
                    *(uint4*)((u16*)Cv + (size_t)row * ldc + col) = v;
            }
        }
    } else {
        int crow = bm + wm * 128 + (g << 2);
        int ccol = bn + wn * 64 + lr;
        #pragma unroll
        for (int n = 0; n < 4; ++n) {
            int col = ccol + n * 16;
            if (col < N) {
                float bv = bias ? bias[col] : 0.f;
                #pragma unroll
                for (int m = 0; m < 8; ++m) {
                    #pragma unroll
                    for (int j = 0; j < 4; ++j) {
                        int row = crow + m * 16 + j;
                        ((float*)Cv)[(size_t)row * ldc + col] = acc[m][n][j] + bv;
                    }
                }
            }
        }
    }
}

// ---------- LayerNorm (in place on bf16 u), vectorized ----------
__global__ __launch_bounds__(256) void layernorm_k(u16* __restrict__ u,
                                                   const float* __restrict__ g,
                                                   const float* __restrict__ bt) {
    int row = blockIdx.x, t = threadIdx.x;
    u16* p = u + (size_t)row * D_MODELx;
    ushort4 v4 = *(ushort4*)(p + t * 4);
    float v[4] = {b2f(v4.x), b2f(v4.y), b2f(v4.z), b2f(v4.w)};
    float s = v[0] + v[1] + v[2] + v[3];
    float mean = block_sum(s) * (1.f / D_MODELx);
    float vs = 0.f;
    #pragma unroll
    for (int i = 0; i < 4; ++i) { float d = v[i] - mean; vs += d * d; }
    float var = block_sum(vs) * (1.f / D_MODELx);
    float inv = rsqrtf(var + 1e-5f);
    ushort4 o;
    o.x = f2b((v[0] - mean) * inv * g[t * 4 + 0] + bt[t * 4 + 0]);
    o.y = f2b((v[1] - mean) * inv * g[t * 4 + 1] + bt[t * 4 + 1]);
    o.z = f2b((v[2] - mean) * inv * g[t * 4 + 2] + bt[t * 4 + 2]);
    o.w = f2b((v[3] - mean) * inv * g[t * 4 + 3] + bt[t * 4 + 3]);
    *(ushort4*)(p + t * 4) = o;
}

// ---------- dt softplus + per-chunk cumsum: one wave per (b,h,c) ----------
__global__ __launch_bounds__(256) void dt_acs_k(const u16* __restrict__ xb,
                                                const float* __restrict__ dt_bias,
                                                const float* __restrict__ A_log,
                                                float* __restrict__ dtv, float* __restrict__ acs) {
    int gid = blockIdx.x * 4 + (threadIdx.x >> 6);
    int lane = threadIdx.x & 63;
    int c = gid & 31;
    int h = (gid >> 5) & 31;
    int b = gid >> 10;
    float A = -expf(A_log[h]);
    int row = b * LSEQ + c * CHUNKx + lane;
    float x = b2f(xb[(size_t)row * LDX + XB_DT + h]) + dt_bias[h];
    float d = (x > 20.f) ? x : log1pf(expf(x));
    dtv[(size_t)row * NHEADSx + h] = d;
    float v = A * d;
    #pragma unroll
    for (int off = 1; off < 64; off <<= 1) {
        float t = __shfl_up(v, off);
        if (lane >= off) v += t;
    }
    acs[(((size_t)(b * NHEADSx + h)) * NCHUNKx + c) * CHUNKx + lane] = v;
}

// ---------- causal depthwise conv (k=4) + SiLU, in place, 8-ch vectorized ----------
__global__ __launch_bounds__(256) void conv_k(u16* __restrict__ xb,
                                              const float* __restrict__ w,
                                              const float* __restrict__ bias) {
    int chgl = threadIdx.x & 3, seg = threadIdx.x >> 2;
    int ch0 = (blockIdx.x * 4 + chgl) * 8;
    int b = blockIdx.y;
    float4 wv[8];
    float bs[8];
    #pragma unroll
    for (int j = 0; j < 8; ++j) wv[j] = *(const float4*)(w + (size_t)(ch0 + j) * 4);
    #pragma unroll
    for (int j = 0; j < 8; ++j) bs[j] = bias[ch0 + j];
    size_t base = ((size_t)b * LSEQ + seg * 32) * LDX + ch0;
    float h0[8] = {}, h1[8] = {}, h2[8] = {};
    if (seg) {
        up8(*(const uint4*)(xb + base - 3 * (size_t)LDX), h0);
        up8(*(const uint4*)(xb + base - 2 * (size_t)LDX), h1);
        up8(*(const uint4*)(xb + base - 1 * (size_t)LDX), h2);
    }
    __syncthreads();
    for (int i = 0; i < 32; ++i) {
        float xl[8], o[8];
        up8(*(const uint4*)(xb + base + (size_t)i * LDX), xl);
        #pragma unroll
        for (int j = 0; j < 8; ++j) {
            float v = fmaf(wv[j].w, xl[j], fmaf(wv[j].z, h2[j],
                      fmaf(wv[j].y, h1[j], fmaf(wv[j].x, h0[j], bs[j]))));
            o[j] = silu_f(v);
            h0[j] = h1[j]; h1[j] = h2[j]; h2[j] = xl[j];
        }
        *(uint4*)(xb + base + (size_t)i * LDX) = pk8(o);
    }
}

// ---------- fused SSD v3 (round-6 proven version) ----------
__global__ __launch_bounds__(512) void ssd_k(u16* __restrict__ xb,
                                             const float* __restrict__ dtv,
                                             const float* __restrict__ acs,
                                             const float* __restrict__ Dp) {
    __shared__ u16 Xt[64 * 72];
    __shared__ u16 Bl[64 * 136];
    __shared__ u16 Bt[128 * 72];
    __shared__ u16 Cl[64 * 136];
    __shared__ u16 Gp[64 * 72];
    __shared__ u16 Sp[64 * 136];
    __shared__ float acss[64], eaS[64], dtS[64], ddS[64];
    __shared__ float dcS;

    int h = blockIdx.x, b = blockIdx.y;
    int tid = threadIdx.x;
    int w = tid >> 6, lane = tid & 63, l15 = lane & 15, g = lane >> 4;
    int lt = w >> 1, hf = w & 1;
    float Dh = Dp[h];

    int sr = tid >> 3, scq = tid & 7;
    int srh = sr >> 3, srl = sr & 7;
    int sgrp = ((srh ^ scq) << 3) + srl;

    f32x4 sreg[4];
    #pragma unroll
    for (int pt = 0; pt < 4; ++pt) sreg[pt] = (f32x4){0.f, 0.f, 0.f, 0.f};

    const float* acb = acs + ((size_t)(b * NHEADSx + h)) * NCHUNKx * CHUNKx;

    for (int i = tid; i < 64 * 136 / 8; i += 512) ((uint4*)Sp)[i] = (uint4){0, 0, 0, 0};

    if (tid < 64) {
        float a = acb[tid];
        float a63 = __shfl(a, 63);
        float d = dtv[(size_t)(b * LSEQ + tid) * NHEADSx + h];
        acss[tid] = a; eaS[tid] = __expf(a); dtS[tid] = d;
        ddS[tid] = d * __expf(a63 - a);
        if (tid == 0) dcS = __expf(a63);
    }
    uint4 rXs, rB0, rB1, rC0, rC1;
    {
        size_t rowb = ((size_t)(b * LSEQ) + sr) * LDX;
        rXs = *(const uint4*)(xb + rowb + h * 64 + scq * 8);
        rB0 = *(const uint4*)(xb + rowb + XB_B + scq * 8);
        rB1 = *(const uint4*)(xb + rowb + XB_B + 64 + scq * 8);
        rC0 = *(const uint4*)(xb + rowb + XB_C + scq * 8);
        rC1 = *(const uint4*)(xb + rowb + XB_C + 64 + scq * 8);
    }
    __syncthreads();
    {
        *(uint4*)&Bl[sr * 136 + scq * 8] = rB0;
        *(uint4*)&Bl[sr * 136 + 64 + scq * 8] = rB1;
        *(uint4*)&Cl[sr * 136 + scq * 8] = rC0;
        *(uint4*)&Cl[sr * 136 + 64 + scq * 8] = rC1;
        const u16* px = (const u16*)&rXs;
        const u16* pb0 = (const u16*)&rB0;
        const u16* pb1 = (const u16*)&rB1;
        float dd = ddS[sr];
        #pragma unroll
        for (int j = 0; j < 8; ++j) {
            Xt[(scq * 8 + j) * 72 + sgrp] = px[j];
            Bt[(scq * 8 + j) * 72 + sgrp] = f2b(b2f(pb0[j]) * dd);
            Bt[(64 + scq * 8 + j) * 72 + sgrp] = f2b(b2f(pb1[j]) * dd);
        }
    }
    __syncthreads();

    for (int c = 0; c < NCHUNKx; ++c) {
        int row0 = b * LSEQ + c * CHUNKx;
        if (c + 1 < NCHUNKx) {
            size_t rowb = ((size_t)row0 + CHUNKx + sr) * LDX;
            rXs = *(const uint4*)(xb + rowb + h * 64 + scq * 8);
            rB0 = *(const uint4*)(xb + rowb + XB_B + scq * 8);
            rB1 = *(const uint4*)(xb + rowb + XB_B + 64 + scq * 8);
            rC0 = *(const uint4*)(xb + rowb + XB_C + scq * 8);
            rC1 = *(const uint4*)(xb + rowb + XB_C + 64 + scq * 8);
        }
        f32x4 accG[2], yac[2];
        accG[0] = (f32x4){0.f, 0.f, 0.f, 0.f}; accG[1] = (f32x4){0.f, 0.f, 0.f, 0.f};
        yac[0] = (f32x4){0.f, 0.f, 0.f, 0.f};  yac[1] = (f32x4){0.f, 0.f, 0.f, 0.f};
        #pragma unroll
        for (int kk = 0; kk < 4; ++kk) {
            bf16x8 aC = *(bf16x8*)&Cl[(16 * lt + l15) * 136 + 32 * kk + 8 * g];
            #pragma unroll
            for (int q = 0; q < 2; ++q) {
                int st = 16 * (2 * hf + q) + l15;
                bf16x8 bB = *(bf16x8*)&Bl[st * 136 + 32 * kk + 8 * g];
                accG[q] = __builtin_amdgcn_mfma_f32_16x16x32_bf16(aC, bB, accG[q], 0, 0, 0);
                bf16x8 bS = *(bf16x8*)&Sp[st * 136 + 32 * kk + 8 * g];
                yac[q] = __builtin_amdgcn_mfma_f32_16x16x32_bf16(aC, bS, yac[q], 0, 0, 0);
            }
        }
        float dc = dcS;
        #pragma unroll
        for (int q = 0; q < 2; ++q) {
            int s = 16 * (2 * hf + q) + l15;
            float as = acss[s], ds = dtS[s];
            #pragma unroll
            for (int j = 0; j < 4; ++j) {
                int l = 16 * lt + 4 * g + j;
                yac[q][j] *= eaS[l];
                float v = (s <= l) ? accG[q][j] * __expf(acss[l] - as) * ds : 0.f;
                Gp[l * 72 + s] = f2b(v);
            }
        }
        #pragma unroll
        for (int pt = 0; pt < 4; ++pt)
            #pragma unroll
            for (int j = 0; j < 4; ++j) sreg[pt][j] *= dc;
        __syncthreads();

        #pragma unroll
        for (int kk = 0; kk < 2; ++kk) {
            bf16x8 aG = *(bf16x8*)&Gp[(16 * lt + l15) * 72 + 32 * kk + 8 * g];
            #pragma unroll
            for (int q = 0; q < 2; ++q) {
                int row = 16 * (2 * hf + q) + l15;
                int grp = (4 * kk + g) ^ ((row >> 3) & 7);
                bf16x8 bXq = *(bf16x8*)&Xt[row * 72 + grp * 8];
                yac[q] = __builtin_amdgcn_mfma_f32_16x16x32_bf16(aG, bXq, yac[q], 0, 0, 0);
            }
            int rowb = 16 * w + l15;
            int grpb = (4 * kk + g) ^ ((rowb >> 3) & 7);
            bf16x8 aB = *(bf16x8*)&Bt[rowb * 72 + grpb * 8];
            #pragma unroll
            for (int pt = 0; pt < 4; ++pt) {
                int row = 16 * pt + l15;
                int grp = (4 * kk + g) ^ ((row >> 3) & 7);
                bf16x8 bX = *(bf16x8*)&Xt[row * 72 + grp * 8];
                sreg[pt] = __builtin_amdgcn_mfma_f32_16x16x32_bf16(aB, bX, sreg[pt], 0, 0, 0);
            }
        }
        #pragma unroll
        for (int q = 0; q < 2; ++q) {
            int p = 16 * (2 * hf + q) + l15;
            int ph = (p >> 3) & 7;
            #pragma unroll
            for (int j = 0; j < 4; ++j) {
                int l = 16 * lt + 4 * g + j;
                int col = (((l >> 3) ^ ph) << 3) + (l & 7);
                float xsv = b2f(Xt[p * 72 + col]);
                xb[(size_t)(row0 + l) * LDX + h * 64 + p] = f2b(yac[q][j] + Dh * xsv);
            }
        }
        if (tid < 64 && c + 1 < NCHUNKx) {
            float a = acb[(c + 1) * CHUNKx + tid];
            float a63 = __shfl(a, 63);
            float d = dtv[(size_t)(row0 + CHUNKx + tid) * NHEADSx + h];
            acss[tid] = a; eaS[tid] = __expf(a); dtS[tid] = d;
            ddS[tid] = d * __expf(a63 - a);
            if (tid == 0) dcS = __expf(a63);
        }
        __syncthreads();
        #pragma unroll
        for (int pt = 0; pt < 4; ++pt) {
            ushort4 pk;
            pk.x = f2b(sreg[pt][0]); pk.y = f2b(sreg[pt][1]);
            pk.z = f2b(sreg[pt][2]); pk.w = f2b(sreg[pt][3]);
            *(ushort4*)&Sp[(16 * pt + l15) * 136 + 16 * w + 4 * g] = pk;
        }
        if (c + 1 < NCHUNKx) {
            *(uint4*)&Bl[sr * 136 + scq * 8] = rB0;
            *(uint4*)&Bl[sr * 136 + 64 + scq * 8] = rB1;
            *(uint4*)&Cl[sr * 136 + scq * 8] = rC0;
            *(uint4*)&Cl[sr * 136 + 64 + scq * 8] = rC1;
            const u16* px = (const u16*)&rXs;
            const u16* pb0 = (const u16*)&rB0;
            const u16* pb1 = (const u16*)&rB1;
            float dd = ddS[sr];
            #pragma unroll
            for (int j = 0; j < 8; ++j) {
                Xt[(scq * 8 + j) * 72 + sgrp] = px[j];
                Bt[(scq * 8 + j) * 72 + sgrp] = f2b(b2f(pb0[j]) * dd);
                Bt[(64 + scq * 8 + j) * 72 + sgrp] = f2b(b2f(pb1[j]) * dd);
            }
        }
        __syncthreads();
    }
}

// ---------- gated RMSNorm in place over y, vectorized ----------
__global__ __launch_bounds__(256) void rmsgate_k(u16* __restrict__ xb,
                                                 const u16* __restrict__ zb,
                                                 const float* __restrict__ w) {
    int row = blockIdx.x, t = threadIdx.x;
    const u16* zp = zb + (size_t)row * D_INNERx;
    u16* yp = xb + (size_t)row * LDX;
    float zf[8], yf[8], vals[8];
    up8(*(const uint4*)(zp + t * 8), zf);
    up8(*(const uint4*)(yp + t * 8), yf);
    float ss = 0.f;
    #pragma unroll
    for (int i = 0; i < 8; ++i) {
        float y = yf[i] * silu_f(zf[i]);
        vals[i] = y; ss += y * y;
    }
    float tot = block_sum(ss);
    float scale = rsqrtf(tot * (1.f / D_INNERx) + 1e-5f);
    #pragma unroll
    for (int i = 0; i < 8; ++i) vals[i] *= scale * w[t * 8 + i];
    *(uint4*)(yp + t * 8) = pk8(vals);
}

// ---------- hidden = out[:, -1, :] ----------
__global__ void hidden_k(float* __restrict__ out) {
    int i = blockIdx.x * blockDim.x + threadIdx.x;
    int b = i >> 10, d = i & 1023;
    out[(size_t)NTOK * D_MODELx + i] = out[((size_t)(b * LSEQ + LSEQ - 1)) * D_MODELx + d];
}

extern "C" void kernel_launch(void* const* d_in, const int* in_sizes, int n_in,
                              void* d_out, int out_size, void* d_ws, size_t ws_size,
                              hipStream_t stream) {
    const float* x       = (const float*)d_in[0];
    const float* Wi      = (const float*)d_in[1];
    const float* bi      = (const float*)d_in[2];
    const float* ln_g    = (const float*)d_in[3];
    const float* ln_b    = (const float*)d_in[4];
    const float* Win     = (const float*)d_in[5];
    const float* conv_w  = (const float*)d_in[6];
    const float* conv_b  = (const float*)d_in[7];
    const float* dt_bias = (const float*)d_in[8];
    const float* A_log   = (const float*)d_in[9];
    const float* Dv      = (const float*)d_in[10];
    const float* rms_w   = (const float*)d_in[11];
    const float* Wout    = (const float*)d_in[12];
    float* out = (float*)d_out;

    if (ws_size < 118489088ull) return;
    u16* xb  = (u16*)d_ws;                                   // [NTOK][LDX] bf16
    u16* ub  = xb + (size_t)NTOK * LDX;                      // [NTOK][1024] bf16
    u16* Woutb = ub;                                         // overlay after y ready
    u16* Rb  = ub + (size_t)NTOK * D_MODELx;                 // 8 MiB region
    u16* Wib  = Rb;                                          // 1024x1024
    u16* Winb = Rb + (size_t)1024 * 1024;                    // up to 2560x1024 (padded)
    float* acs = (float*)Rb;                                 // overlays Wib/Winb after GEMMs
    float* dtv = acs + (size_t)B_N * NHEADSx * NCHUNKx * CHUNKx;
    u16* xbf = xb;
    u16* zb  = (u16*)d_out;

    // 0. conversions
    cvt_f2b_k<<<16384, 256, 0, stream>>>(x, xbf, 16777216 / 4);
    cvt_f2b_k<<<1024, 256, 0, stream>>>(Wi, Wib, 1048576 / 4);
    // 1. u = x @ Wi^T + bi
    gemm_big<1><<<dim3(4, 64), 512, 0, stream>>>(
        xbf, Wib, bi, ub, NTOK, D_MODELx, D_INx, D_INx, D_MODELx);
    // 2. LayerNorm
    layernorm_k<<<NTOK, 256, 0, stream>>>(ub, ln_g, ln_b);
    // 3a. z = u @ Win[0:2048]^T -> d_out
    cvt_f2b_k<<<2048, 256, 0, stream>>>(Win, Winb, (2048 * 1024) / 4);
    gemm_big<1><<<dim3(8, 64), 512, 0, stream>>>(
        ub, Winb, nullptr, zb, NTOK, D_INNERx, D_MODELx, D_MODELx, D_INNERx);
    // 3b. xBCdt = u @ Win[2048:4384]^T -> xb  (N=2336 ragged; Winb padded to 2560 rows)
    cvt_f2b_k<<<2336, 256, 0, stream>>>(Win + (size_t)2048 * 1024, Winb, (2336 * 1024) / 4);
    gemm_big<1><<<dim3(10, 64), 512, 0, stream>>>(
        ub, Winb, nullptr, xb, NTOK, LDX, D_MODELx, D_MODELx, LDX);
    // 4. dt + per-chunk cumsum (wave-parallel scan)
    dt_acs_k<<<2048, 256, 0, stream>>>(xb, dt_bias, A_log, dtv, acs);
    // 5. conv + silu in place (8-ch vectorized, 576 blocks)
    conv_k<<<dim3(CONV_DIMx / 32, B_N), 256, 0, stream>>>(xb, conv_w, conv_b);
    // 6+7. fused SSD v3
    ssd_k<<<dim3(NHEADSx, B_N), 512, 0, stream>>>(xb, dtv, acs, Dv);
    // 8. gated RMSNorm in place over y
    rmsgate_k<<<NTOK, 256, 0, stream>>>(xb, zb, rms_w);
    // 9. out = yn @ Wout^T
    cvt_f2b_k<<<2048, 256, 0, stream>>>(Wout, Woutb, (2048 * 1024) / 4);
    gemm_big<0><<<dim3(4, 64), 512, 0, stream>>>(
        xb, Woutb, nullptr, out, NTOK, D_MODELx, D_INNERx, LDX, D_MODELx);
    // 10. hidden
    hidden_k<<<(B_N * D_MODELx) / 256, 256, 0, stream>>>(out);
}